// Round 4
// baseline (753.500 us; speedup 1.0000x reference)
//
#include <hip/hip_runtime.h>
#include <hip/hip_bf16.h>
#include <math.h>

#define B_Q   128
#define DIM   512
#define NCORP 500000
#define TR    128           // corpus rows per block tile
#define NCH   16            // K chunks of 32 (512/32)

typedef short short8 __attribute__((ext_vector_type(8)));
typedef float floatx4 __attribute__((ext_vector_type(4)));

__device__ __forceinline__ unsigned short bf16_rne(float x) {
    unsigned u = __float_as_uint(x);
    return (unsigned short)((u + 0x7FFFu + ((u >> 16) & 1u)) >> 16);
}

__device__ __forceinline__ short bf16s(float x) {
    return (short)bf16_rne(x);
}

__device__ __forceinline__ void ins3(float s, int id,
                                     float& b0, float& b1, float& b2,
                                     int& i0, int& i1, int& i2) {
    if (s > b0)      { b2 = b1; i2 = i1; b1 = b0; i1 = i0; b0 = s; i0 = id; }
    else if (s > b1) { b2 = b1; i2 = i1; b1 = s;  i1 = id; }
    else if (s > b2) { b2 = s;  i2 = id; }
}

__device__ __forceinline__ void ins2(float s, int id,
                                     float& b0, float& b1, int& i0, int& i1) {
    if (s > b0)      { b1 = b0; i1 = i0; b0 = s; i0 = id; }
    else if (s > b1) { b1 = s;  i1 = id; }
}

__device__ __forceinline__ void ins8(float s, int id, float* bs, int* bi) {
#pragma unroll
    for (int j = 0; j < 8; ++j) {
        if (s > bs[j]) {
            float tf = bs[j]; int tx = bi[j];
            bs[j] = s; bi[j] = id; s = tf; id = tx;
        }
    }
}

// async global -> LDS, 16B per lane, linear dest (wave-uniform base + lane*16)
__device__ __forceinline__ void gload16(const float* g, float* l) {
    __builtin_amdgcn_global_load_lds(
        (const __attribute__((address_space(1))) unsigned*)g,
        (__attribute__((address_space(3))) unsigned*)l, 16, 0, 0);
}

// ---------------------------------------------------------------------------
// Kernel A: query = query_r @ W ; L2-normalize ; write
//  (a) exact qn f32 row-major  (for rescore)
//  (b) bf16 MFMA B-fragment-linear layout:
//      qfrag idx = kc*4096 + qg*512 + (g*16 + q15)*8 + e
// ---------------------------------------------------------------------------
__global__ void proj_kernel(const float* __restrict__ qr,
                            const float* __restrict__ W,
                            float* __restrict__ qn,
                            unsigned short* __restrict__ qfrag) {
    __shared__ float qrow[DIM];
    __shared__ float red[256];
    const int b = blockIdx.x;
    const int t = threadIdx.x;

    qrow[t]       = qr[b * DIM + t];
    qrow[t + 256] = qr[b * DIM + t + 256];
    __syncthreads();

    float acc0 = 0.f, acc1 = 0.f;
#pragma unroll 8
    for (int k = 0; k < DIM; ++k) {
        const float q = qrow[k];
        acc0 = fmaf(q, W[k * DIM + t],       acc0);
        acc1 = fmaf(q, W[k * DIM + t + 256], acc1);
    }

    red[t] = acc0 * acc0 + acc1 * acc1;
    __syncthreads();
    for (int s = 128; s > 0; s >>= 1) {
        if (t < s) red[t] += red[t + s];
        __syncthreads();
    }
    const float inv = 1.0f / fmaxf(sqrtf(red[0]), 1e-6f);

    const int qg = b >> 4, q15 = b & 15;
#pragma unroll
    for (int half = 0; half < 2; ++half) {
        const int d = t + half * 256;
        const float x = (half == 0 ? acc0 : acc1) * inv;
        qn[b * DIM + d] = x;
        const int kc = d >> 5, kk = d & 31, g = kk >> 3, e = kk & 7;
        qfrag[(size_t)kc * 4096 + qg * 512 + (g * 16 + q15) * 8 + e] = bf16_rne(x);
    }
}

// ---------------------------------------------------------------------------
// Kernel B: bf16 MFMA cosine scan (approx ranking) + per-block top-k.
// Corpus staged f32 via global_load_lds (linear dest, inverse-swizzled source,
// swizzled ds_read). Q fragments read straight from L2. No reg staging -> no
// spills. Norms from the lane's own f32 fragment elems + shfl reduce.
// ---------------------------------------------------------------------------
__global__ __launch_bounds__(256, 2) void scan_bf16_kernel(
        const float* __restrict__ corpus,
        const unsigned short* __restrict__ qfrag,
        float* __restrict__ cand_s,
        int*   __restrict__ cand_i,
        int nblk) {
    __shared__ __align__(16) float As[2][4096];    // 2 x 16 KB f32 chunk tiles

    const int t = threadIdx.x;
    const int w = t >> 6, l = t & 63;

    // staging geometry: issue i covers LDS slots (w*4+i)*64 + l  (16B slots)
    const int srow0 = w * 32 + (l >> 3);                       // + i*8
    const int kswf  = ((l & 7) ^ ((l >> 3) & 7)) * 4;          // f32 offset in row
    // read geometry
    const int h = l >> 4;                                      // 0..3 (k-slice)
    const int arow0 = w * 32 + (l & 15);                       // + rg*16
    const int sw0 = ((h * 2 + 0) ^ (l & 7)) * 4;
    const int sw1 = ((h * 2 + 1) ^ (l & 7)) * 4;

    float ts[8][2]; int ti[8][2];
#pragma unroll
    for (int qg = 0; qg < 8; ++qg) {
        ts[qg][0] = -1e30f; ts[qg][1] = -1e30f;
        ti[qg][0] = -1;     ti[qg][1] = -1;
    }

    const int ntiles = (NCORP + TR - 1) / TR;
    for (int tile = blockIdx.x; tile < ntiles; tile += nblk) {
        const int r0 = tile * TR;
        floatx4 acc[2][8];
#pragma unroll
        for (int rg = 0; rg < 2; ++rg)
#pragma unroll
            for (int qg = 0; qg < 8; ++qg)
#pragma unroll
                for (int j = 0; j < 4; ++j) acc[rg][qg][j] = 0.f;
        float nsq0 = 0.f, nsq1 = 0.f;

        // prologue: stage chunk 0 into As[0]
#pragma unroll
        for (int i = 0; i < 4; ++i) {
            int rr = r0 + srow0 + i * 8; if (rr > NCORP - 1) rr = NCORP - 1;
            gload16(corpus + (size_t)rr * DIM + kswf, &As[0][(w * 4 + i) * 256]);
        }
        __syncthreads();

        for (int kc = 0; kc < NCH; ++kc) {
            const int d = kc & 1;

            // Q fragment loads (L2-resident) -- issued BEFORE next-chunk
            // global_load_lds so the MFMA's vmcnt wait doesn't drain them.
            const short8* qp = (const short8*)(qfrag + (size_t)kc * 4096);
            short8 bq[8];
#pragma unroll
            for (int qg = 0; qg < 8; ++qg) bq[qg] = qp[qg * 64 + l];
            __builtin_amdgcn_sched_barrier(0);

            if (kc + 1 < NCH) {
#pragma unroll
                for (int i = 0; i < 4; ++i) {
                    int rr = r0 + srow0 + i * 8; if (rr > NCORP - 1) rr = NCORP - 1;
                    gload16(corpus + (size_t)rr * DIM + (kc + 1) * 32 + kswf,
                            &As[d ^ 1][(w * 4 + i) * 256]);
                }
            }

            // A fragments from LDS (swizzled) + f32 norms + cvt to bf16
            const float* Ad = &As[d][0];
            const float* b0p = Ad + arow0 * 32;
            const float* b1p = Ad + (arow0 + 16) * 32;
            const float4 f0 = *(const float4*)(b0p + sw0);
            const float4 f1 = *(const float4*)(b0p + sw1);
            const float4 f2 = *(const float4*)(b1p + sw0);
            const float4 f3 = *(const float4*)(b1p + sw1);

            nsq0 += f0.x*f0.x + f0.y*f0.y + f0.z*f0.z + f0.w*f0.w
                  + f1.x*f1.x + f1.y*f1.y + f1.z*f1.z + f1.w*f1.w;
            nsq1 += f2.x*f2.x + f2.y*f2.y + f2.z*f2.z + f2.w*f2.w
                  + f3.x*f3.x + f3.y*f3.y + f3.z*f3.z + f3.w*f3.w;

            short8 a0, a1;
            a0[0]=bf16s(f0.x); a0[1]=bf16s(f0.y); a0[2]=bf16s(f0.z); a0[3]=bf16s(f0.w);
            a0[4]=bf16s(f1.x); a0[5]=bf16s(f1.y); a0[6]=bf16s(f1.z); a0[7]=bf16s(f1.w);
            a1[0]=bf16s(f2.x); a1[1]=bf16s(f2.y); a1[2]=bf16s(f2.z); a1[3]=bf16s(f2.w);
            a1[4]=bf16s(f3.x); a1[5]=bf16s(f3.y); a1[6]=bf16s(f3.z); a1[7]=bf16s(f3.w);

#pragma unroll
            for (int qg = 0; qg < 8; ++qg) {
                acc[0][qg] = __builtin_amdgcn_mfma_f32_16x16x32_bf16(a0, bq[qg], acc[0][qg], 0, 0, 0);
                acc[1][qg] = __builtin_amdgcn_mfma_f32_16x16x32_bf16(a1, bq[qg], acc[1][qg], 0, 0, 0);
            }
            __syncthreads();
        }

        // full row norms: lanes l, l^16, l^32, l^48 cover the 4 k-slices
        nsq0 += __shfl_xor(nsq0, 16); nsq0 += __shfl_xor(nsq0, 32);
        nsq1 += __shfl_xor(nsq1, 16); nsq1 += __shfl_xor(nsq1, 32);
        const float inv0 = 1.0f / fmaxf(sqrtf(nsq0), 1e-6f);
        const float inv1 = 1.0f / fmaxf(sqrtf(nsq1), 1e-6f);

        // scores -> per-lane running top2 per query slot
#pragma unroll
        for (int reg = 0; reg < 4; ++reg) {
            const int m = h * 4 + reg;            // C-row within 16 (lane>>4)*4+reg
            const float iva = __shfl(inv0, m, 64);
            const float ivb = __shfl(inv1, m, 64);
            const int ra = r0 + w * 32 + m;
            const int rb = ra + 16;
            if (ra < NCORP) {
#pragma unroll
                for (int qg = 0; qg < 8; ++qg)
                    ins2(acc[0][qg][reg] * iva, ra, ts[qg][0], ts[qg][1], ti[qg][0], ti[qg][1]);
            }
            if (rb < NCORP) {
#pragma unroll
                for (int qg = 0; qg < 8; ++qg)
                    ins2(acc[1][qg][reg] * ivb, rb, ts[qg][0], ts[qg][1], ti[qg][0], ti[qg][1]);
            }
        }
        __syncthreads();   // all waves done with As before next tile restages
    }

    // block merge: 16 slots x 2 per query -> per-block top-3 (reuse As)
    float* msc = (float*)As;                   // [128][16][2] = 16 KB
    int*   mid = (int*)&As[1][0];              // [128][16][2] = 16 KB
#pragma unroll
    for (int qg = 0; qg < 8; ++qg) {
        const int q = qg * 16 + (l & 15);
        const int slot = w * 4 + h;
#pragma unroll
        for (int j = 0; j < 2; ++j) {
            msc[(q * 16 + slot) * 2 + j] = ts[qg][j];
            mid[(q * 16 + slot) * 2 + j] = ti[qg][j];
        }
    }
    __syncthreads();
    if (t < B_Q) {
        float b0 = -1e30f, b1 = -1e30f, b2 = -1e30f;
        int   i0 = -1, i1 = -1, i2 = -1;
        for (int e = 0; e < 32; ++e)
            ins3(msc[t * 32 + e], mid[t * 32 + e], b0, b1, b2, i0, i1, i2);
        const size_t base = ((size_t)blockIdx.x * B_Q + t) * 3;
        cand_s[base + 0] = b0; cand_s[base + 1] = b1; cand_s[base + 2] = b2;
        cand_i[base + 0] = i0; cand_i[base + 1] = i1; cand_i[base + 2] = i2;
    }
}

// ---------------------------------------------------------------------------
// Kernel C: merge per-block candidates -> global approx top-8 per query.
// ---------------------------------------------------------------------------
__global__ void merge_topk_kernel(const float* __restrict__ cand_s,
                                  const int*   __restrict__ cand_i,
                                  int nblk,
                                  float* __restrict__ topT_s,
                                  int*   __restrict__ topT_i) {
    __shared__ float ls[256 * 8];
    __shared__ int   li[256 * 8];
    const int q = blockIdx.x;
    const int t = threadIdx.x;

    float bs[8]; int bi[8];
#pragma unroll
    for (int j = 0; j < 8; ++j) { bs[j] = -1e30f; bi[j] = -1; }

    for (int blk = t; blk < nblk; blk += 256) {
        const size_t base = ((size_t)blk * B_Q + q) * 3;
#pragma unroll
        for (int j = 0; j < 3; ++j)
            ins8(cand_s[base + j], cand_i[base + j], bs, bi);
    }
#pragma unroll
    for (int j = 0; j < 8; ++j) { ls[t * 8 + j] = bs[j]; li[t * 8 + j] = bi[j]; }
    __syncthreads();

    for (int s = 128; s > 0; s >>= 1) {
        if (t < s) {
#pragma unroll
            for (int j = 0; j < 8; ++j)
                ins8(ls[(t + s) * 8 + j], li[(t + s) * 8 + j], bs, bi);
#pragma unroll
            for (int j = 0; j < 8; ++j) { ls[t * 8 + j] = bs[j]; li[t * 8 + j] = bi[j]; }
        }
        __syncthreads();
    }
    if (t == 0) {
#pragma unroll
        for (int j = 0; j < 8; ++j) { topT_s[q * 8 + j] = bs[j]; topT_i[q * 8 + j] = bi[j]; }
    }
}

// ---------------------------------------------------------------------------
// Kernel D: exact f32 rescore of 8 candidates per query -> top-3 -> out.
// d_out: [0..383] scores f32, [384..767] indices stored as f32 values.
// ---------------------------------------------------------------------------
__global__ void rescore_kernel(const float* __restrict__ corpus,
                               const float* __restrict__ qn,
                               const int*   __restrict__ topT_i,
                               float* __restrict__ out) {
    __shared__ float qrow[DIM];
    __shared__ float sc[8];
    const int q = blockIdx.x;
    const int t = threadIdx.x;
    const int g = t >> 5;       // candidate 0..7
    const int lane = t & 31;

    qrow[t]       = qn[q * DIM + t];
    qrow[t + 256] = qn[q * DIM + t + 256];
    __syncthreads();

    const int r = topT_i[q * 8 + g];
    float d = 0.f, n = 0.f;
    if (r >= 0) {
        const float* row = corpus + (size_t)r * DIM;
        for (int j = lane; j < DIM; j += 32) {
            const float c = row[j];
            d = fmaf(qrow[j], c, d);
            n = fmaf(c, c, n);
        }
    }
#pragma unroll
    for (int m = 16; m > 0; m >>= 1) {
        d += __shfl_xor(d, m);
        n += __shfl_xor(n, m);
    }
    if (lane == 0)
        sc[g] = (r >= 0) ? d / fmaxf(sqrtf(n), 1e-6f) : -1e30f;
    __syncthreads();

    if (t == 0) {
        float b0 = -1e30f, b1 = -1e30f, b2 = -1e30f;
        int   i0 = 0, i1 = 0, i2 = 0;
#pragma unroll
        for (int e = 0; e < 8; ++e)
            ins3(sc[e], topT_i[q * 8 + e], b0, b1, b2, i0, i1, i2);
        out[q * 3 + 0] = b0;
        out[q * 3 + 1] = b1;
        out[q * 3 + 2] = b2;
        out[B_Q * 3 + q * 3 + 0] = (float)i0;
        out[B_Q * 3 + q * 3 + 1] = (float)i1;
        out[B_Q * 3 + q * 3 + 2] = (float)i2;
    }
}

// ---------------------------------------------------------------------------
extern "C" void kernel_launch(void* const* d_in, const int* in_sizes, int n_in,
                              void* d_out, int out_size, void* d_ws, size_t ws_size,
                              hipStream_t stream) {
    const float* qr     = (const float*)d_in[0];  // [128,512]
    const float* corpus = (const float*)d_in[1];  // [500000,512]
    const float* W      = (const float*)d_in[2];  // [512,512]

    float* out = (float*)d_out;
    char*  ws  = (char*)d_ws;

    float*          qn     = (float*)ws;                      // 256 KB
    unsigned short* qfrag  = (unsigned short*)(ws + 262144);  // 128 KB
    float*          topT_s = (float*)(ws + 393216);           // 4 KB
    int*            topT_i = (int*)(ws + 397312);             // 4 KB
    const size_t head = 401408;

    const int ntiles = (NCORP + TR - 1) / TR;                 // 3907
    const size_t per_blk = (size_t)B_Q * 3 * (sizeof(float) + sizeof(int));
    int nblk = ntiles;
    const size_t avail = ws_size > head ? ws_size - head : 0;
    if ((size_t)nblk * per_blk > avail) nblk = (int)(avail / per_blk);
    if (nblk < 1) nblk = 1;

    float* cand_s = (float*)(ws + head);
    int*   cand_i = (int*)(ws + head + (size_t)nblk * B_Q * 3 * sizeof(float));

    proj_kernel<<<B_Q, 256, 0, stream>>>(qr, W, qn, qfrag);
    scan_bf16_kernel<<<nblk, 256, 0, stream>>>(corpus, qfrag, cand_s, cand_i, nblk);
    merge_topk_kernel<<<B_Q, 256, 0, stream>>>(cand_s, cand_i, nblk, topT_s, topT_i);
    rescore_kernel<<<B_Q, 256, 0, stream>>>(corpus, qn, topT_i, out);
}